// Round 4
// baseline (163.997 us; speedup 1.0000x reference)
//
#include <hip/hip_runtime.h>

#define TT 14
#define LL 26
#define EE 128
#define NB 16384
#define BPB 8              // batches per block
#define ROWS (BPB * TT)    // 112 (b,t) rows per block
#define EPAD 27            // odd pad -> bank-bijective emis writes

// ---------------------------------------------------------------------------
// Setup: fold conv into an effective emission matrix.
//   Weff[e][l] = sum_{ky,kx} conv_w[ky][kx] * Wmat[l][oy*8+ox]
//   be[l]      = conv_b * sum_e Wmat[l][e]
// ---------------------------------------------------------------------------
__global__ __launch_bounds__(256) void crf_setup(
    const float* __restrict__ conv_w, const float* __restrict__ conv_b,
    const float* __restrict__ params, float* __restrict__ weff,
    float* __restrict__ be) {
  int idx = blockIdx.x * 256 + threadIdx.x;
  if (idx < EE * LL) {
    int e = idx / LL, l = idx - e * LL;
    int iy = e >> 3, ix = e & 7;
    float s = 0.f;
    for (int ky = 0; ky < 5; ++ky) {
      int oy = iy - ky + 2;
      if (oy < 0 || oy >= 16) continue;
      for (int kx = 0; kx < 5; ++kx) {
        int ox = ix - kx + 2;
        if (ox < 0 || ox >= 8) continue;
        s += conv_w[ky * 5 + kx] * params[l * EE + oy * 8 + ox];
      }
    }
    weff[e * LL + l] = s;  // [e][l]: main-kernel reads are wave-uniform
  }
  if (idx < LL) {
    float s = 0.f;
    for (int e = 0; e < EE; ++e) s += params[idx * EE + e];
    be[idx] = conv_b[0] * s;
  }
}

// ---------------------------------------------------------------------------
// Fused emission GEMM + Viterbi + backtrack. One block = 8 batches.
// GEMM: 2 threads per (b,t) row, wave-uniform label-half split (13 labels
// each) -> weff stays in SGPRs, occupancy doubles, summation order identical.
// ---------------------------------------------------------------------------
__global__ __launch_bounds__(256, 8) void crf_main(
    const float* __restrict__ X, const float* __restrict__ params,
    const float* __restrict__ weff, const float* __restrict__ be,
    float* __restrict__ out) {
  __shared__ float emis_s[ROWS * EPAD];            // 12096 B
  __shared__ float Ts[LL * LL];                    // 2704 B
  __shared__ unsigned char bp_s[BPB][TT - 1][28];  // 2912 B

  const int tid = threadIdx.x;
  const int b0 = blockIdx.x * BPB;

  for (int i = tid; i < LL * LL; i += 256) Ts[i] = params[LL * EE + i];

  // ---- Phase 1: emissions. half = tid>>7 is wave-uniform (waves 0,1 -> half
  //      0; waves 2,3 -> half 1). Thread (half, r) computes labels
  //      [13*half, 13*half+13) of row r.
  {
    const int half = tid >> 7;  // wave-uniform
    const int r = tid & 127;    // row within block
    if (r < ROWS) {
      const float4* xv =
          reinterpret_cast<const float4*>(X) + (size_t)(b0 * TT + r) * 32;
      const int lb = half * 13;  // wave-uniform label base
      float acc[13];
#pragma unroll
      for (int l = 0; l < 13; ++l) acc[l] = 0.f;
      for (int c = 0; c < 16; ++c) {
        float4 v0 = xv[c * 2 + 0];
        float4 v1 = xv[c * 2 + 1];
        const float* w = weff + c * 8 * LL + lb;  // wave-uniform -> s_load
#pragma unroll
        for (int l = 0; l < 13; ++l)
          acc[l] += v0.x * w[l] + v0.y * w[LL + l] + v0.z * w[2 * LL + l] +
                    v0.w * w[3 * LL + l];
#pragma unroll
        for (int l = 0; l < 13; ++l)
          acc[l] += v1.x * w[4 * LL + l] + v1.y * w[5 * LL + l] +
                    v1.z * w[6 * LL + l] + v1.w * w[7 * LL + l];
      }
#pragma unroll
      for (int l = 0; l < 13; ++l)
        emis_s[r * EPAD + lb + l] = acc[l] + be[lb + l];  // be: s_load
    }
  }
  __syncthreads();

  // ---- Phase 2: Viterbi. 8 groups of 32 lanes, group g = batch g, lane j =
  //      label. Single pass (no p-loop).
  const int g = tid >> 5;                  // 0..7
  const int j = tid & 31;
  const int jj = (j < LL) ? j : (LL - 1);

  float Tcol[LL];
#pragma unroll
  for (int i = 0; i < LL; ++i) Tcol[i] = Ts[i * LL + jj];  // Trans[i][j]

  float alpha = emis_s[(g * TT + 0) * EPAD + jj];
  for (int t = 1; t < TT; ++t) {
    float m = -__builtin_inff();
    int bp = 0;
#pragma unroll
    for (int i = 0; i < LL; ++i) {
      float a_i = __shfl(alpha, i, 32);
      float s = a_i + Tcol[i];
      if (s > m) { m = s; bp = i; }        // strict > : first-index tie-break
    }
    alpha = m + emis_s[(g * TT + t) * EPAD + jj];
    if (j < LL) bp_s[g][t - 1][j] = (unsigned char)bp;
  }

  // argmax over labels (max value, lowest index on tie)
  float val = (j < LL) ? alpha : -__builtin_inff();
  int idx = j;
#pragma unroll
  for (int off = 16; off >= 1; off >>= 1) {
    float v2 = __shfl_xor(val, off, 32);
    int i2 = __shfl_xor(idx, off, 32);
    if (v2 > val || (v2 == val && i2 < idx)) { val = v2; idx = i2; }
  }

  __syncthreads();  // bp_s writes visible before backtrack

  if (j == 0) {
    const int b = b0 + g;
    out[(size_t)NB * TT + b] = val;  // score
    int lbl = idx;
    for (int t = TT - 1; t >= 1; --t) {
      out[(size_t)b * TT + t] = (float)lbl;
      lbl = bp_s[g][t - 1][lbl];
    }
    out[(size_t)b * TT + 0] = (float)lbl;
  }
}

extern "C" void kernel_launch(void* const* d_in, const int* in_sizes, int n_in,
                              void* d_out, int out_size, void* d_ws,
                              size_t ws_size, hipStream_t stream) {
  const float* X = (const float*)d_in[0];
  const float* conv_w = (const float*)d_in[1];
  const float* conv_b = (const float*)d_in[2];
  const float* params = (const float*)d_in[3];
  float* out = (float*)d_out;
  float* weff = (float*)d_ws;  // 3328 floats
  float* be = weff + EE * LL;  // 26 floats

  hipLaunchKernelGGL(crf_setup, dim3(13), dim3(256), 0, stream, conv_w, conv_b,
                     params, weff, be);
  hipLaunchKernelGGL(crf_main, dim3(NB / BPB), dim3(256), 0, stream, X, params,
                     weff, be, out);
}

// Round 5
// 94.411 us; speedup vs baseline: 1.7371x; 1.7371x over previous
//
#include <hip/hip_runtime.h>

#define TT 14
#define LL 26
#define EE 128
#define NB 16384
#define BPB 8              // batches per block
#define ROWS (BPB * TT)    // 112 (b,t) rows per block
#define EPAD 27            // odd pad -> bank-bijective emis writes

// ---------------------------------------------------------------------------
// Setup: fold conv into an effective emission matrix.
//   Weff[e][l] = sum_{ky,kx} conv_w[ky][kx] * Wmat[l][oy*8+ox]
//   be[l]      = conv_b * sum_e Wmat[l][e]
// ---------------------------------------------------------------------------
__global__ __launch_bounds__(256) void crf_setup(
    const float* __restrict__ conv_w, const float* __restrict__ conv_b,
    const float* __restrict__ params, float* __restrict__ weff,
    float* __restrict__ be) {
  int idx = blockIdx.x * 256 + threadIdx.x;
  if (idx < EE * LL) {
    int e = idx / LL, l = idx - e * LL;
    int iy = e >> 3, ix = e & 7;
    float s = 0.f;
    for (int ky = 0; ky < 5; ++ky) {
      int oy = iy - ky + 2;
      if (oy < 0 || oy >= 16) continue;
      for (int kx = 0; kx < 5; ++kx) {
        int ox = ix - kx + 2;
        if (ox < 0 || ox >= 8) continue;
        s += conv_w[ky * 5 + kx] * params[l * EE + oy * 8 + ox];
      }
    }
    weff[e * LL + l] = s;  // [e][l]: main-kernel reads are wave-uniform
  }
  if (idx < LL) {
    float s = 0.f;
    for (int e = 0; e < EE; ++e) s += params[idx * EE + e];
    be[idx] = conv_b[0] * s;
  }
}

// ---------------------------------------------------------------------------
// Fused emission GEMM + Viterbi + backtrack. One block = 8 batches.
// GEMM: R1 mapping (1 thread = 1 row, 26 acc) but X is burst-preloaded into
// registers 16 float4 at a time (2 passes) for memory-level parallelism.
// W chunks stay at 104 floats (R1-proven s_load codegen).
// ---------------------------------------------------------------------------
__global__ __launch_bounds__(128, 4) void crf_main(
    const float* __restrict__ X, const float* __restrict__ params,
    const float* __restrict__ weff, const float* __restrict__ be,
    float* __restrict__ out) {
  __shared__ float emis_s[ROWS * EPAD];            // 12096 B
  __shared__ float Ts[LL * LL];                    // 2704 B
  __shared__ unsigned char bp_s[BPB][TT - 1][28];  // 2912 B

  const int tid = threadIdx.x;
  const int b0 = blockIdx.x * BPB;

  for (int i = tid; i < LL * LL; i += 128) Ts[i] = params[LL * EE + i];

  // ---- Phase 1: emissions.
  if (tid < ROWS) {
    const float4* xv =
        reinterpret_cast<const float4*>(X) + (size_t)(b0 * TT + tid) * 32;
    float acc[LL];
#pragma unroll
    for (int l = 0; l < LL; ++l) acc[l] = 0.f;

#pragma unroll
    for (int p = 0; p < 2; ++p) {
      // Burst: 16 independent loads in flight (statically indexed -> VGPRs).
      float4 xb[16];
#pragma unroll
      for (int c = 0; c < 16; ++c) xb[c] = xv[p * 16 + c];
      // Compute: R1's exact body, e ascending -> bit-identical summation.
#pragma unroll
      for (int c = 0; c < 16; ++c) {
        const float4 v = xb[c];
        const float* w = weff + (p * 16 + c) * 4 * LL;  // uniform -> s_load
#pragma unroll
        for (int l = 0; l < LL; ++l)
          acc[l] += v.x * w[l] + v.y * w[LL + l] + v.z * w[2 * LL + l] +
                    v.w * w[3 * LL + l];
      }
    }
#pragma unroll
    for (int l = 0; l < LL; ++l) emis_s[tid * EPAD + l] = acc[l] + be[l];
  }
  __syncthreads();

  // ---- Phase 2: Viterbi. Each 32-lane group owns one batch, lane j = label.
  const int lane = tid & 63;
  const int wv = tid >> 6;                 // wave 0..1
  const int j = lane & 31;
  const int hb = lane >> 5;
  const int jj = (j < LL) ? j : (LL - 1);

  float Tcol[LL];
#pragma unroll
  for (int i = 0; i < LL; ++i) Tcol[i] = Ts[i * LL + jj];  // Trans[i][j]

  for (int p = 0; p < 2; ++p) {
    const int bl = p * 4 + wv * 2 + hb;    // 0..7

    float alpha = emis_s[(bl * TT + 0) * EPAD + jj];
    for (int t = 1; t < TT; ++t) {
      float m = -__builtin_inff();
      int bp = 0;
#pragma unroll
      for (int i = 0; i < LL; ++i) {
        float a_i = __shfl(alpha, i, 32);
        float s = a_i + Tcol[i];
        if (s > m) { m = s; bp = i; }      // strict > : first-index tie-break
      }
      alpha = m + emis_s[(bl * TT + t) * EPAD + jj];
      if (j < LL) bp_s[bl][t - 1][j] = (unsigned char)bp;
    }

    // argmax over labels (max value, lowest index on tie)
    float val = (j < LL) ? alpha : -__builtin_inff();
    int idx = j;
#pragma unroll
    for (int off = 16; off >= 1; off >>= 1) {
      float v2 = __shfl_xor(val, off, 32);
      int i2 = __shfl_xor(idx, off, 32);
      if (v2 > val || (v2 == val && i2 < idx)) { val = v2; idx = i2; }
    }

    __syncthreads();  // bp_s writes visible before backtrack

    if (j == 0) {
      const int b = b0 + bl;
      out[(size_t)NB * TT + b] = val;  // score
      int lbl = idx;
      for (int t = TT - 1; t >= 1; --t) {
        out[(size_t)b * TT + t] = (float)lbl;
        lbl = bp_s[bl][t - 1][lbl];
      }
      out[(size_t)b * TT + 0] = (float)lbl;
    }
    __syncthreads();
  }
}

extern "C" void kernel_launch(void* const* d_in, const int* in_sizes, int n_in,
                              void* d_out, int out_size, void* d_ws,
                              size_t ws_size, hipStream_t stream) {
  const float* X = (const float*)d_in[0];
  const float* conv_w = (const float*)d_in[1];
  const float* conv_b = (const float*)d_in[2];
  const float* params = (const float*)d_in[3];
  float* out = (float*)d_out;
  float* weff = (float*)d_ws;  // 3328 floats
  float* be = weff + EE * LL;  // 26 floats

  hipLaunchKernelGGL(crf_setup, dim3(13), dim3(256), 0, stream, conv_w, conv_b,
                     params, weff, be);
  hipLaunchKernelGGL(crf_main, dim3(NB / BPB), dim3(128), 0, stream, X, params,
                     weff, be, out);
}